// Round 13
// baseline (1310.511 us; speedup 1.0000x reference)
//
#include <hip/hip_runtime.h>

// PoseSPDecoderKT — round 12 (= round 10/11 resubmitted; two consecutive
// UnresponsiveContainer infra failures on the same pod, no kernel execution).
// SP anti-alias padding (conv1 67, conv2 54, conv3 38, conv4 26) kills the
// systematic inter-quarter LDS bank aliasing (SQ_LDS_BANK_CONFLICT=6.29M in
// rounds 6-8). Tail fix: LDS A buffer padded to TOTAP=(TOTA+63)&~63 chunks;
// global source chunk index clamped to TOTA-1 (LDS dest is hardware
// base+lane*16 and lands in the allocated pad). conv1 frag-read uses
// truncation hi-split. Everything else identical to round 8.

typedef unsigned short u16;
typedef unsigned short u16x4 __attribute__((ext_vector_type(4)));
typedef unsigned short u16x8 __attribute__((ext_vector_type(8)));
typedef float f32x4 __attribute__((ext_vector_type(4)));
typedef __bf16 bf16x8 __attribute__((ext_vector_type(8)));

__constant__ int KPAR_C[21] = {0,0,0,1,2,3,4,5,6,7,8,9,9,9,12,13,14,16,17,18,19};

__device__ __forceinline__ u16 bf16rne(float v) {
  unsigned b = __builtin_bit_cast(unsigned, v);
  return (u16)((b + 0x7fffu + ((b >> 16) & 1u)) >> 16);
}
__device__ __forceinline__ float bf16tof(u16 h) {
  unsigned b = ((unsigned)h) << 16;
  return __builtin_bit_cast(float, b);
}
__device__ __forceinline__ f32x4 mfma16(u16x8 a, u16x8 b, f32x4 c) {
  return __builtin_amdgcn_mfma_f32_16x16x32_bf16(
      __builtin_bit_cast(bf16x8, a), __builtin_bit_cast(bf16x8, b), c, 0, 0, 0);
}
__device__ __forceinline__ int unpack_c(int p) {
  return (p & ~31) | (((p >> 3) & 3) << 2) | (p & 3) | ((p & 4) << 2);
}
__device__ __forceinline__ void gload_lds16(const void* g, void* l) {
  __builtin_amdgcn_global_load_lds((const __attribute__((address_space(1))) void*)g,
                                   (__attribute__((address_space(3))) void*)l, 16, 0, 0);
}
// anti-alias slot count: f32 path wants SP odd; bf16 path wants SP%8 in {2,6}
constexpr int pickSP(int rows, bool f32) {
  int sp = rows + 2;
  if (f32) {
    if ((sp & 1) == 0) sp += 1;
  } else {
    while ((sp % 8) != 2 && (sp % 8) != 6) ++sp;
  }
  return sp;
}

// ---------------- kwprep: conv weights + tok_w -> fragment-order tiles ------
__global__ __launch_bounds__(256)
void kwprep(const float* __restrict__ conv1_w, const float* __restrict__ up_w,
            const float* __restrict__ tok_w, u16* __restrict__ WF, u16* __restrict__ TWF) {
  int idx = blockIdx.x * 256 + threadIdx.x;
  if (idx < 786432) {
    const int lane = idx & 63;
    int r = idx >> 6;
    const int nf = r & 15; r >>= 4;
    const int ks = r % 48; r /= 48;
    const int p = r & 1; r >>= 1;
    const int nh = r & 1;
    const int L = r >> 1;
    const float* Wsrc = (L == 0) ? conv1_w : (up_w + (size_t)(L - 1) * 786432);
    const int wcol = unpack_c(nh * 256 + nf * 16 + (lane & 15));
    u16x8 o;
#pragma unroll
    for (int e = 0; e < 8; ++e) {
      const int k = ks * 32 + ((lane >> 4) << 2) + (e & 3) + ((e >> 2) << 4);
      const int c = k & 511, kk = k >> 9;
      const float v = Wsrc[(size_t)wcol * 1536 + c * 3 + kk];
      const u16 h = bf16rne(v);
      o[e] = p ? bf16rne(v - bf16tof(h)) : h;
    }
    *(u16x8*)(WF + (size_t)idx * 8) = o;
  } else if (idx < 786432 + 1024) {
    const int i2 = idx - 786432;
    const int lane = i2 & 63;
    const int r = i2 >> 6;
    const int mf = r & 3;
    const int ks = (r >> 2) & 1;
    const int p = r >> 3;
    const int s = mf * 16 + (lane & 15);
    u16x8 o;
#pragma unroll
    for (int e = 0; e < 8; ++e) {
      const int t = ks * 32 + ((lane >> 4) << 2) + (e & 3) + ((e >> 2) << 4);
      const float v = tok_w[s * 64 + t];
      const u16 h = bf16rne(v);
      o[e] = p ? bf16rne(v - bf16tof(h)) : h;
    }
    *(u16x8*)(TWF + (size_t)i2 * 8) = o;
  }
}

// ---------------- kpw1prep: pw1 -> fragment-order split tiles ---------------
__global__ __launch_bounds__(256)
void kpw1prep(const float* __restrict__ pw1, u16* __restrict__ PWF) {
  const int idx = blockIdx.x * 256 + threadIdx.x;
  if (idx >= 2752512) return;
  const int lane = idx & 63;
  const int nf = (idx >> 6) & 15;
  const int ks = (idx >> 10) & 31;
  const int p = (idx >> 15) & 1;
  const int nh = (idx >> 16) & 1;
  const int j = idx >> 17;
  const int w = unpack_c(nh * 256 + nf * 16 + (lane & 15));
  u16x8 o;
#pragma unroll
  for (int e = 0; e < 8; ++e) {
    const int k = ks * 32 + ((lane >> 4) << 2) + (e & 3) + ((e >> 2) << 4);
    const float v = pw1[((size_t)j * 1024 + k) * 512 + w];
    const u16 h = bf16rne(v);
    o[e] = p ? bf16rne(v - bf16tof(h)) : h;
  }
  *(u16x8*)(PWF + (size_t)idx * 8) = o;
}

// ---------------- conv GEMM: cs-major, dbuf-A, anti-alias SP ----------------
template <int SLOT, int ROWS, bool SRCF32, bool F32OUT, bool RELU>
__global__ __launch_bounds__(512, 2)
void conv_gemm(const float* __restrict__ xf,
               const u16* __restrict__ ghi, const u16* __restrict__ glo,
               const u16* __restrict__ wl,
               const float* __restrict__ bias,
               u16* __restrict__ ohi, u16* __restrict__ olo,
               float* __restrict__ of32) {
  constexpr int MFW = SLOT / 16;
  constexpr int SP = pickSP(ROWS, SRCF32);
  constexpr int TOTA = 32 * SP;                    // valid chunks per A buffer
  constexpr int TOTAP = (TOTA + 63) & ~63;         // padded (wave-granular) size
  constexpr int HALF = ((TOTA / 2) + 63) & ~63;    // wave-granular split point
  __shared__ u16x8 Ald[2][TOTAP];                  // dbuf A (pad absorbs tail writes)
  __shared__ u16x8 Bld[2][2][16][64];              // dbuf B (64 KB)

  const int tid = threadIdx.x, lane = tid & 63, w = tid >> 6;
  const int mw = w & 3, nw = w >> 2;               // 4 m-waves (batch) x 2 n-waves
  const int bid = blockIdx.x;
  const int nh = (bid >> 3) & 1;                   // pair ids differ by 8 -> same XCD
  const int bg = ((bid >> 4) << 3) | (bid & 7);
  const int bb0 = bg * 4;

  f32x4 acc[MFW][8];
#pragma unroll
  for (int m = 0; m < MFW; ++m)
#pragma unroll
    for (int n = 0; n < 8; ++n) acc[m][n] = (f32x4){0.f, 0.f, 0.f, 0.f};

  auto ASTAGE = [&](int cs1, int dst, int LO, int HI) {
#pragma unroll
    for (int it = 0; it * 512 < TOTAP; ++it) {
      const int base = it * 512 + w * 64;          // wave-uniform
      if (base >= LO && base < HI && base < TOTAP) {
        int c = base + lane;
        if (c > TOTA - 1) c = TOTA - 1;            // clamp SOURCE (dest pads ok)
        const int s = c % SP;
        const int g = c / SP;
        int row = s - 1;
        row = row < 0 ? 0 : (row > ROWS - 1 ? ROWS - 1 : row);
        if constexpr (SRCF32) {
          const int q8 = g & 7, bm = g >> 3;
          const float* src = xf + ((size_t)(bb0 + bm) * ROWS + row) * 512 +
                             cs1 * 32 + ((q8 >> 1) << 2) + ((q8 & 1) << 4);
          gload_lds16(src, (u16*)&Ald[dst][0] + (size_t)base * 8);
        } else {
          const int q = g & 3, bm = (g >> 2) & 3, pl = g >> 4;
          const u16* srcp = pl ? glo : ghi;
          const u16* src = srcp + ((size_t)(bb0 + bm) * ROWS + row) * 512 +
                           cs1 * 32 + q * 8;
          gload_lds16(src, (u16*)&Ald[dst][0] + (size_t)base * 8);
        }
      }
    }
  };
  auto BSTAGE = [&](int step, int buf) {
    const int ks2 = (step % 3) * 16 + (step / 3);  // = kk*16 + cs
#pragma unroll
    for (int ci = 0; ci < 4; ++ci) {
      const int cch = w + ci * 8;
      const int p = cch >> 4, nf = cch & 15;
      gload_lds16(wl + ((size_t)(((nh * 2 + p) * 48 + ks2) * 16 + nf)) * 512 + lane * 8,
                  &Bld[buf][p][nf][0]);
    }
  };

  ASTAGE(0, 0, 0, TOTAP);
  BSTAGE(0, 0);
  __syncthreads();

  const int Q = lane >> 4;
  for (int cs = 0; cs < 16; ++cs) {
    const int ab = cs & 1;
#pragma unroll
    for (int kk = 0; kk < 3; ++kk) {
      const int step = cs * 3 + kk;
      if (step < 47) BSTAGE(step + 1, (step + 1) & 1);
      if (cs < 15) {
        if (kk == 0) ASTAGE(cs + 1, ab ^ 1, 0, HALF);
        if (kk == 1) ASTAGE(cs + 1, ab ^ 1, HALF, TOTAP);
      }
      u16x8 ah[MFW], al[MFW];
#pragma unroll
      for (int m = 0; m < MFW; ++m) {
        int s = m * 16 + (lane & 15) + kk;
        if (s > SP - 1) s = SP - 1;                // junk rows masked at epilogue
        if constexpr (SRCF32) {
          const f32x4 va = *(const f32x4*)&Ald[ab][(mw * 8 + 2 * Q) * SP + s];
          const f32x4 vb = *(const f32x4*)&Ald[ab][(mw * 8 + 2 * Q + 1) * SP + s];
          const float vv[8] = {va[0], va[1], va[2], va[3], vb[0], vb[1], vb[2], vb[3]};
#pragma unroll
          for (int e = 0; e < 8; ++e) {
            // truncation hi-split: hi = top16(v); lo = RNE(v - hi)
            const unsigned b = __builtin_bit_cast(unsigned, vv[e]);
            ah[m][e] = (u16)(b >> 16);
            const float hif = __builtin_bit_cast(float, b & 0xFFFF0000u);
            al[m][e] = bf16rne(vv[e] - hif);
          }
        } else {
          ah[m] = Ald[ab][(mw * 4 + Q) * SP + s];
          al[m] = Ald[ab][((4 + mw) * 4 + Q) * SP + s];
        }
      }
      const int bbuf = step & 1;
      __builtin_amdgcn_s_setprio(1);
#pragma unroll
      for (int n = 0; n < 8; ++n) {
        const u16x8 bh = Bld[bbuf][0][nw * 8 + n][lane];
        const u16x8 bl = Bld[bbuf][1][nw * 8 + n][lane];
#pragma unroll
        for (int m = 0; m < MFW; ++m) {
          acc[m][n] = mfma16(ah[m], bh, acc[m][n]);
          acc[m][n] = mfma16(ah[m], bl, acc[m][n]);
          acc[m][n] = mfma16(al[m], bh, acc[m][n]);
        }
      }
      __builtin_amdgcn_s_setprio(0);
      __syncthreads();
    }
  }

  const int b = bb0 + mw;
#pragma unroll
  for (int m = 0; m < MFW; ++m) {
#pragma unroll
    for (int n = 0; n < 8; ++n) {
      const int col = nh * 256 + nw * 128 + n * 16 + (lane & 15);  // packed slot
      const float bs = bias[unpack_c(col)];
#pragma unroll
      for (int r = 0; r < 4; ++r) {
        const int t = m * 16 + ((lane >> 4) << 2) + r;
        if (t < ROWS) {
          float v = acc[m][n][r] + bs;
          if (RELU) v = fmaxf(v, 0.f);
          const size_t o = ((size_t)b * ROWS + t) * 512 + col;
          if constexpr (F32OUT) {
            of32[o] = v;
          } else {
            const u16 h = bf16rne(v);
            ohi[o] = h;
            olo[o] = bf16rne(v - bf16tof(h));
          }
        }
      }
    }
  }
}

// ---------------- tok_mix (unchanged) ---------------------------------------
__global__ __launch_bounds__(512, 2)
void tok_mix(const u16* __restrict__ h1hi, const u16* __restrict__ h1lo,
             const u16* __restrict__ twf, const float* __restrict__ tok_b,
             u16* __restrict__ g1hi, u16* __restrict__ g1lo) {
  __shared__ float h1f[64][258];
  __shared__ u16x8 twl[2][2][4][64];
  __shared__ float tbl[64];
  const int tid = threadIdx.x, lane = tid & 63, w = tid >> 6;
  const int mw = w & 3, nw = w >> 2;
  const int b = blockIdx.y, ch = blockIdx.x;

  for (int i = tid; i < 1024; i += 512) ((u16x8*)twl)[i] = ((const u16x8*)twf)[i];
  if (tid < 64) tbl[tid] = tok_b[tid];
  for (int i = tid; i < 2048; i += 512) {
    const int t = i >> 5, c8 = (i & 31) * 8;
    const size_t o = ((size_t)b * 64 + t) * 512 + ch * 256 + c8;
    const u16x8 hv = *(const u16x8*)(h1hi + o);
    const u16x8 lv = *(const u16x8*)(h1lo + o);
#pragma unroll
    for (int e = 0; e < 8; ++e) h1f[t][c8 + e] = bf16tof(hv[e]) + bf16tof(lv[e]);
  }
  __syncthreads();

  f32x4 acc2[8];
#pragma unroll
  for (int n = 0; n < 8; ++n) acc2[n] = (f32x4){0.f, 0.f, 0.f, 0.f};
#pragma unroll
  for (int ksI = 0; ksI < 2; ++ksI) {
    const u16x8 ah = twl[0][ksI][mw][lane];
    const u16x8 al = twl[1][ksI][mw][lane];
    const int t0 = ksI * 32 + ((lane >> 4) << 2);
#pragma unroll
    for (int n = 0; n < 8; ++n) {
      const int c = nw * 128 + n * 16 + (lane & 15);
      u16x8 bh, bl;
#pragma unroll
      for (int e = 0; e < 8; ++e) {
        const float v = h1f[t0 + (e & 3) + ((e >> 2) << 4)][c];
        const u16 h = bf16rne(v);
        bh[e] = h;
        bl[e] = bf16rne(v - bf16tof(h));
      }
      acc2[n] = mfma16(ah, bh, acc2[n]);
      acc2[n] = mfma16(ah, bl, acc2[n]);
      acc2[n] = mfma16(al, bh, acc2[n]);
    }
  }
  __syncthreads();
#pragma unroll
  for (int n = 0; n < 8; ++n) {
    const int c = nw * 128 + n * 16 + (lane & 15);
#pragma unroll
    for (int r = 0; r < 4; ++r) {
      const int s = mw * 16 + ((lane >> 4) << 2) + r;
      h1f[s][c] = fmaxf(acc2[n][r] + tbl[s], 0.f);
    }
  }
  __syncthreads();
  const float scale = (float)(64.0 / 50.0);
  for (int i = tid; i < 50 * 256; i += 512) {
    const int s = i >> 8, c = i & 255;
    float coords = fminf(fmaxf(((float)s + 0.5f) * scale - 0.5f, 0.f), 63.f);
    const int lo = (int)floorf(coords);
    const int hi = lo + 1 < 64 ? lo + 1 : 63;
    const float wv = coords - (float)lo;
    const float v = h1f[lo][c] * (1.f - wv) + h1f[hi][c] * wv;
    const u16 h = bf16rne(v);
    const size_t o = ((size_t)b * 50 + s) * 512 + ch * 256 + c;
    g1hi[o] = h;
    g1lo[o] = bf16rne(v - bf16tof(h));
  }
}

// ---------------- ginterp (unchanged) ---------------------------------------
template <int SOUT, int SIN>
__global__ __launch_bounds__(256)
void ginterp(const u16* __restrict__ ahi, const u16* __restrict__ alo,
             u16* __restrict__ ghi, u16* __restrict__ glo) {
  const int idx = blockIdx.x * 256 + threadIdx.x;
  if (idx >= 1024 * SOUT * 64) return;
  const int ch = (idx & 63) * 8;
  const int s = (idx >> 6) % SOUT;
  const int b = (idx >> 6) / SOUT;
  const float scale = (float)((double)SIN / (double)SOUT);
  float coords = fminf(fmaxf(((float)s + 0.5f) * scale - 0.5f, 0.f), (float)(SIN - 1));
  const int lo = (int)floorf(coords);
  const int hi = lo + 1 < SIN ? lo + 1 : SIN - 1;
  const float wv = coords - (float)lo;
  const size_t olo_ = ((size_t)b * SIN + lo) * 512 + ch;
  const size_t ohi_ = ((size_t)b * SIN + hi) * 512 + ch;
  const u16x8 vh0 = *(const u16x8*)(ahi + olo_), vl0 = *(const u16x8*)(alo + olo_);
  const u16x8 vh1 = *(const u16x8*)(ahi + ohi_), vl1 = *(const u16x8*)(alo + ohi_);
  u16x8 oh, ol;
#pragma unroll
  for (int e = 0; e < 8; ++e) {
    const float v0 = bf16tof(vh0[e]) + bf16tof(vl0[e]);
    const float v1 = bf16tof(vh1[e]) + bf16tof(vl1[e]);
    const float v = v0 * (1.f - wv) + v1 * wv;
    const u16 h = bf16rne(v);
    oh[e] = h;
    ol[e] = bf16rne(v - bf16tof(h));
  }
  const size_t oo = ((size_t)b * SOUT + s) * 512 + ch;
  *(u16x8*)(ghi + oo) = oh;
  *(u16x8*)(glo + oo) = ol;
}

// ---------------- k_beta (unchanged) ----------------------------------------
__global__ __launch_bounds__(256)
void k_beta(const float* __restrict__ h, const float* __restrict__ ln_g,
            const float* __restrict__ ln_b, const float* __restrict__ beta_w,
            const float* __restrict__ beta_b, float* __restrict__ out) {
  __shared__ float nbuf[512];
  __shared__ float red[32];
  __shared__ float part[160];
  const int tid = threadIdx.x;
  const int b = blockIdx.x;
  const float* hb = h + (size_t)b * (22 * 512);
  float m0 = 0.f, m1 = 0.f;
  for (int t = 0; t < 22; ++t) {
    m0 += hb[t * 512 + tid];
    m1 += hb[t * 512 + tid + 256];
  }
  m0 *= (1.f / 22.f);
  m1 *= (1.f / 22.f);
  float s = m0 + m1, sq = m0 * m0 + m1 * m1;
  for (int off = 32; off > 0; off >>= 1) {
    s += __shfl_down(s, off);
    sq += __shfl_down(sq, off);
  }
  const int lane = tid & 63, wid = tid >> 6;
  if (lane == 0) { red[wid] = s; red[8 + wid] = sq; }
  __syncthreads();
  if (tid == 0) {
    float S = red[0] + red[1] + red[2] + red[3];
    float Q = red[8] + red[9] + red[10] + red[11];
    float mu = S * (1.f / 512.f);
    float var = Q * (1.f / 512.f) - mu * mu;
    red[16] = mu;
    red[17] = 1.f / sqrtf(var + 1e-5f);
  }
  __syncthreads();
  const float mu = red[16], rs = red[17];
  const int uc = unpack_c(tid);
  nbuf[tid] = (m0 - mu) * rs * ln_g[uc] + ln_b[uc];
  nbuf[tid + 256] = (m1 - mu) * rs * ln_g[uc + 256] + ln_b[uc + 256];
  __syncthreads();
  if (tid < 160) {
    const int o = tid >> 4, l = tid & 15;
    float p = 0.f;
    for (int w = l; w < 512; w += 16) p += nbuf[w] * beta_w[unpack_c(w) * 10 + o];
    part[tid] = p;
  }
  __syncthreads();
  if (tid < 10) {
    float p = beta_b[tid];
#pragma unroll
    for (int l = 0; l < 16; ++l) p += part[tid * 16 + l];
    out[(size_t)b * 10 + tid] = p;
  }
}

// ---------------- k_pose1 (unchanged) ---------------------------------------
__global__ __launch_bounds__(512, 2)
void k_pose1(const float* __restrict__ hf, const u16* __restrict__ PWF,
             const float* __restrict__ pb1,
             u16* __restrict__ hidhi, u16* __restrict__ hidlo) {
  __shared__ u16x8 Ald[2][2][8][64];
  __shared__ u16x8 Bld[2][2][16][64];
  const int tid = threadIdx.x, lane = tid & 63, w = tid >> 6;
  const int mw = w & 1, nw = w >> 1;
  const int mb = blockIdx.x & 7, nh = blockIdx.x >> 3;
  const int j = blockIdx.y;
  const int bb0 = mb * 128;
  const int par = KPAR_C[j];
  const size_t pwbase = (size_t)(j * 2 + nh) * 524288;

  f32x4 acc[4][4];
#pragma unroll
  for (int m = 0; m < 4; ++m)
#pragma unroll
    for (int n = 0; n < 4; ++n) acc[m][n] = (f32x4){0.f, 0.f, 0.f, 0.f};

  float4 sF0, sF1;

  auto STAGE = [&](int ks, int nb) {
#pragma unroll
    for (int t = 0; t < 4; ++t) {
      const int cc = t * 8 + w;
      const int p = cc >> 4, nf = cc & 15;
      gload_lds16(PWF + pwbase + ((size_t)(p * 32 + ks) * 16 + nf) * 512 + lane * 8,
                  &Bld[nb][p][nf][0]);
    }
  };
  auto LOADSA = [&](int ks) {
    const int row = (ks < 16) ? (j + 1) : par;
    const int b = bb0 + w * 16 + (lane & 15);
    const int pc0 = (ks & 15) * 32 + ((lane >> 4) << 3);
    const float* src = hf + ((size_t)b * 22 + row) * 512 + pc0;
    sF0 = *(const float4*)src;
    sF1 = *(const float4*)(src + 4);
  };
  auto WRITESA = [&](int nb) {
    float vv[8] = {sF0.x, sF0.y, sF0.z, sF0.w, sF1.x, sF1.y, sF1.z, sF1.w};
    u16x8 hv, lv;
#pragma unroll
    for (int e = 0; e < 8; ++e) {
      const u16 h = bf16rne(vv[e]);
      hv[e] = h;
      lv[e] = bf16rne(vv[e] - bf16tof(h));
    }
    Ald[nb][0][w][lane] = hv;
    Ald[nb][1][w][lane] = lv;
  };

  STAGE(0, 0);
  LOADSA(0);
  WRITESA(0);
  __syncthreads();

  for (int ks = 0; ks < 32; ++ks) {
    const int buf = ks & 1;
    if (ks < 31) { STAGE(ks + 1, buf ^ 1); LOADSA(ks + 1); }
    u16x8 ah[4], al[4], bh[4], bl[4];
#pragma unroll
    for (int m = 0; m < 4; ++m) {
      ah[m] = Ald[buf][0][mw * 4 + m][lane];
      al[m] = Ald[buf][1][mw * 4 + m][lane];
    }
#pragma unroll
    for (int n = 0; n < 4; ++n) {
      bh[n] = Bld[buf][0][nw * 4 + n][lane];
      bl[n] = Bld[buf][1][nw * 4 + n][lane];
    }
    __builtin_amdgcn_s_setprio(1);
#pragma unroll
    for (int n = 0; n < 4; ++n)
#pragma unroll
      for (int m = 0; m < 4; ++m) {
        acc[m][n] = mfma16(ah[m], bh[n], acc[m][n]);
        acc[m][n] = mfma16(ah[m], bl[n], acc[m][n]);
        acc[m][n] = mfma16(al[m], bh[n], acc[m][n]);
      }
    __builtin_amdgcn_s_setprio(0);
    if (ks < 31) WRITESA(buf ^ 1);
    __syncthreads();
  }

#pragma unroll
  for (int m = 0; m < 4; ++m) {
#pragma unroll
    for (int n = 0; n < 4; ++n) {
      const int col = nh * 256 + nw * 64 + n * 16 + (lane & 15);
      const float bs = pb1[(size_t)j * 512 + unpack_c(col)];
#pragma unroll
      for (int r = 0; r < 4; ++r) {
        const int b = bb0 + mw * 64 + m * 16 + ((lane >> 4) << 2) + r;
        float v = fmaxf(acc[m][n][r] + bs, 0.f);
        const size_t o = ((size_t)j * 1024 + b) * 512 + col;
        const u16 h = bf16rne(v);
        hidhi[o] = h;
        hidlo[o] = bf16rne(v - bf16tof(h));
      }
    }
  }
}

// ---------------- k_pose2 (unchanged) ---------------------------------------
__global__ __launch_bounds__(256)
void k_pose2(const u16* __restrict__ hidhi, const u16* __restrict__ hidlo,
             const float* __restrict__ pw2, const float* __restrict__ pb2,
             float* __restrict__ out) {
  __shared__ float w2l[3072];
  __shared__ float part[128 * 12];
  const int tid = threadIdx.x;
  const int mb = blockIdx.x, j = blockIdx.y;
  const int bb0 = mb * 128;
  for (int i = tid; i < 3072; i += 256) {
    const int p = i / 6, d = i - p * 6;
    w2l[i] = pw2[(size_t)j * 3072 + unpack_c(p) * 6 + d];
  }
  __syncthreads();

  const int r = tid >> 1, half = tid & 1;
  const int row = bb0 + r;
  const u16* ph = hidhi + ((size_t)j * 1024 + row) * 512 + half * 256;
  const u16* pl = hidlo + ((size_t)j * 1024 + row) * 512 + half * 256;
  float s[6] = {0.f, 0.f, 0.f, 0.f, 0.f, 0.f};
  for (int c = 0; c < 32; ++c) {
    const u16x8 hv = ((const u16x8*)ph)[c];
    const u16x8 lv = ((const u16x8*)pl)[c];
#pragma unroll
    for (int e = 0; e < 8; ++e) {
      const float v = bf16tof(hv[e]) + bf16tof(lv[e]);
      const int hidx = half * 256 + c * 8 + e;
#pragma unroll
      for (int d = 0; d < 6; ++d) s[d] = fmaf(v, w2l[hidx * 6 + d], s[d]);
    }
  }
#pragma unroll
  for (int d = 0; d < 6; ++d) part[r * 12 + half * 6 + d] = s[d];
  __syncthreads();

  if (tid < 128) {
    const int row2 = bb0 + tid;
    float p6[6];
#pragma unroll
    for (int d = 0; d < 6; ++d)
      p6[d] = part[tid * 12 + d] + part[tid * 12 + 6 + d] + pb2[j * 6 + d];
    float* po = out + ((size_t)row2 * 21 + j) * 6;
#pragma unroll
    for (int d = 0; d < 6; ++d) po[d] = p6[d];
    const float a1x = p6[0], a1y = p6[1], a1z = p6[2];
    const float a2x = p6[3], a2y = p6[4], a2z = p6[5];
    const float inv1 = 1.f / sqrtf(a1x * a1x + a1y * a1y + a1z * a1z);
    const float b1x = a1x * inv1, b1y = a1y * inv1, b1z = a1z * inv1;
    const float dot = b1x * a2x + b1y * a2y + b1z * a2z;
    const float px = a2x - dot * b1x, py = a2y - dot * b1y, pz = a2z - dot * b1z;
    const float inv2 = 1.f / sqrtf(px * px + py * py + pz * pz);
    const float b2x = px * inv2, b2y = py * inv2, b2z = pz * inv2;
    const float b3x = b1y * b2z - b1z * b2y;
    const float b3y = b1z * b2x - b1x * b2z;
    const float b3z = b1x * b2y - b1y * b2x;
    float* ro = out + 129024 + ((size_t)row2 * 21 + j) * 9;
    ro[0] = b1x; ro[1] = b1y; ro[2] = b1z;
    ro[3] = b2x; ro[4] = b2y; ro[5] = b2z;
    ro[6] = b3x; ro[7] = b3y; ro[8] = b3z;
  }
}

// ---------------- launch ----------------------------------------------------
extern "C" void kernel_launch(void* const* d_in, const int* in_sizes, int n_in,
                              void* d_out, int out_size, void* d_ws, size_t ws_size,
                              hipStream_t stream) {
  (void)in_sizes; (void)n_in; (void)out_size; (void)ws_size;
  const float* x       = (const float*)d_in[0];
  const float* conv1_w = (const float*)d_in[1];
  const float* conv1_b = (const float*)d_in[2];
  const float* tok_w   = (const float*)d_in[3];
  const float* tok_b   = (const float*)d_in[4];
  const float* up_w    = (const float*)d_in[5];
  const float* up_b    = (const float*)d_in[6];
  const float* ln_g    = (const float*)d_in[7];
  const float* ln_b    = (const float*)d_in[8];
  const float* beta_w  = (const float*)d_in[9];
  const float* beta_b  = (const float*)d_in[10];
  const float* pw1     = (const float*)d_in[11];
  const float* pb1     = (const float*)d_in[12];
  const float* pw2     = (const float*)d_in[13];
  const float* pb2     = (const float*)d_in[14];
  float* outp = (float*)d_out;

  char* base = (char*)d_ws;
  u16* WF  = (u16*)base;                            // 12,582,912 B
  u16* TWF = WF + 6291456;                          // 16,384 B
  u16* PA16 = (u16*)(base + 12599296);              // 134,217,728 B pool A
  u16* PB16 = (u16*)(base + 12599296 + 134217728);  // 104,857,600 B pool B
  u16* h1hi = PA16;            u16* h1lo = PA16 + 33554432;
  u16* a2hi = PA16;            u16* a2lo = PA16 + 26214400;
  u16* a3hi = PA16;            u16* a3lo = PA16 + 18874368;
  float* hf = (float*)PA16;
  u16* g1hi = PB16;            u16* g1lo = PB16 + 26214400;
  u16* g2hi = PB16;            u16* g2lo = PB16 + 18874368;
  u16* g3hi = PB16;            u16* g3lo = PB16 + 11534336;
  u16* PWF   = PB16;
  u16* hidhi = PB16 + 22020096;
  u16* hidlo = PB16 + 33030144;

  const size_t WL = 1572864;

  kwprep<<<3076, 256, 0, stream>>>(conv1_w, up_w, tok_w, WF, TWF);
  conv_gemm<64, 64, true, false, true><<<512, 512, 0, stream>>>(
      x, nullptr, nullptr, WF, conv1_b, h1hi, h1lo, nullptr);
  tok_mix<<<dim3(2, 1024), 512, 0, stream>>>(h1hi, h1lo, TWF, tok_b, g1hi, g1lo);
  conv_gemm<64, 50, false, false, true><<<512, 512, 0, stream>>>(
      nullptr, g1hi, g1lo, WF + WL, up_b, a2hi, a2lo, nullptr);
  ginterp<36, 50><<<9216, 256, 0, stream>>>(a2hi, a2lo, g2hi, g2lo);
  conv_gemm<48, 36, false, false, true><<<512, 512, 0, stream>>>(
      nullptr, g2hi, g2lo, WF + 2 * WL, up_b + 512, a3hi, a3lo, nullptr);
  ginterp<22, 36><<<5632, 256, 0, stream>>>(a3hi, a3lo, g3hi, g3lo);
  conv_gemm<32, 22, false, true, false><<<512, 512, 0, stream>>>(
      nullptr, g3hi, g3lo, WF + 3 * WL, up_b + 1024, nullptr, nullptr, hf);
  kpw1prep<<<10752, 256, 0, stream>>>(pw1, PWF);
  k_pose1<<<dim3(16, 21), 512, 0, stream>>>(hf, PWF, pb1, hidhi, hidlo);
  k_beta<<<1024, 256, 0, stream>>>(hf, ln_g, ln_b, beta_w, beta_b, outp + 322560);
  k_pose2<<<dim3(8, 21), 256, 0, stream>>>(hidhi, hidlo, pw2, pb2, outp);
}

// Round 14
// 1263.284 us; speedup vs baseline: 1.0374x; 1.0374x over previous
//
#include <hip/hip_runtime.h>

// PoseSPDecoderKT — round 13: REVERT conv path to the measured-best round-2
// structure (register-staged A/B, fragment-order LDS, 0 bank conflicts,
// 331 µs @ MfmaUtil 41.6%) after rounds 5-12's slot-A experiments regressed
// it to 403 µs (constant 6.29M conflicts falsified the stride model; the only
// conflict-free b128 pattern is fully-consecutive base+lane*16).
// Two deltas vs round 2: (1) XCD nh-pairing — pair ids differ by 8 -> same
// XCD -> A shared via L2; (2) s_setprio around the MFMA cluster.

typedef unsigned short u16;
typedef unsigned short u16x4 __attribute__((ext_vector_type(4)));
typedef unsigned short u16x8 __attribute__((ext_vector_type(8)));
typedef float f32x4 __attribute__((ext_vector_type(4)));
typedef __bf16 bf16x8 __attribute__((ext_vector_type(8)));

__constant__ int KPAR_C[21] = {0,0,0,1,2,3,4,5,6,7,8,9,9,9,12,13,14,16,17,18,19};

__device__ __forceinline__ u16 bf16rne(float v) {
  unsigned b = __builtin_bit_cast(unsigned, v);
  return (u16)((b + 0x7fffu + ((b >> 16) & 1u)) >> 16);
}
__device__ __forceinline__ float bf16tof(u16 h) {
  unsigned b = ((unsigned)h) << 16;
  return __builtin_bit_cast(float, b);
}
__device__ __forceinline__ f32x4 mfma16(u16x8 a, u16x8 b, f32x4 c) {
  return __builtin_amdgcn_mfma_f32_16x16x32_bf16(
      __builtin_bit_cast(bf16x8, a), __builtin_bit_cast(bf16x8, b), c, 0, 0, 0);
}

// ---------------- kwprep: conv weights + tok_w -> fragment-order tiles ------
__global__ __launch_bounds__(256)
void kwprep(const float* __restrict__ conv1_w, const float* __restrict__ up_w,
            const float* __restrict__ tok_w, u16* __restrict__ WF, u16* __restrict__ TWF) {
  int idx = blockIdx.x * 256 + threadIdx.x;
  if (idx < 786432) {
    const int lane = idx & 63;
    int r = idx >> 6;
    const int nf = r & 15; r >>= 4;
    const int ks = r % 48; r /= 48;
    const int p = r & 1; r >>= 1;
    const int nh = r & 1;
    const int L = r >> 1;
    const float* Wsrc = (L == 0) ? conv1_w : (up_w + (size_t)(L - 1) * 786432);
    const int wcol = nh * 256 + nf * 16 + (lane & 15);
    u16x8 o;
#pragma unroll
    for (int e = 0; e < 8; ++e) {
      const int k = ks * 32 + ((lane >> 4) << 2) + (e & 3) + ((e >> 2) << 4);
      const int c = k & 511, kk = k >> 9;
      const float v = Wsrc[(size_t)wcol * 1536 + c * 3 + kk];
      const u16 h = bf16rne(v);
      o[e] = p ? bf16rne(v - bf16tof(h)) : h;
    }
    *(u16x8*)(WF + (size_t)idx * 8) = o;
  } else if (idx < 786432 + 1024) {
    const int i2 = idx - 786432;
    const int lane = i2 & 63;
    const int r = i2 >> 6;
    const int mf = r & 3;
    const int ks = (r >> 2) & 1;
    const int p = r >> 3;
    const int s = mf * 16 + (lane & 15);
    u16x8 o;
#pragma unroll
    for (int e = 0; e < 8; ++e) {
      const int t = ks * 32 + ((lane >> 4) << 2) + (e & 3) + ((e >> 2) << 4);
      const float v = tok_w[s * 64 + t];
      const u16 h = bf16rne(v);
      o[e] = p ? bf16rne(v - bf16tof(h)) : h;
    }
    *(u16x8*)(TWF + (size_t)i2 * 8) = o;
  }
}

// ---------------- kpw1prep: pw1 -> fragment-order split tiles ---------------
__global__ __launch_bounds__(256)
void kpw1prep(const float* __restrict__ pw1, u16* __restrict__ PWF) {
  const int idx = blockIdx.x * 256 + threadIdx.x;
  if (idx >= 2752512) return;
  const int lane = idx & 63;
  const int nf = (idx >> 6) & 15;
  const int ks = (idx >> 10) & 31;
  const int p = (idx >> 15) & 1;
  const int nh = (idx >> 16) & 1;
  const int j = idx >> 17;
  const int w = nh * 256 + nf * 16 + (lane & 15);
  u16x8 o;
#pragma unroll
  for (int e = 0; e < 8; ++e) {
    const int k = ks * 32 + ((lane >> 4) << 2) + (e & 3) + ((e >> 2) << 4);
    const float v = pw1[((size_t)j * 1024 + k) * 512 + w];
    const u16 h = bf16rne(v);
    o[e] = p ? bf16rne(v - bf16tof(h)) : h;
  }
  *(u16x8*)(PWF + (size_t)idx * 8) = o;
}

// ---------------- conv GEMM (round-2 structure + XCD pairing + setprio) -----
template <int SLOT, int ROWS, bool SRCF32, bool F32OUT, bool RELU>
__global__ __launch_bounds__(512, 2)
void conv_gemm(const float* __restrict__ xf,
               const u16* __restrict__ ghi, const u16* __restrict__ glo,
               const u16* __restrict__ wl,
               const float* __restrict__ bias,
               u16* __restrict__ ohi, u16* __restrict__ olo,
               float* __restrict__ of32) {
  constexpr int MFW = SLOT / 16;
  constexpr int MFT = 4 * MFW;
  constexpr int ASL = (MFT + 7) / 8;
  __shared__ u16x8 Ald[2][2][MFT][64];
  __shared__ u16x8 Bld[2][2][16][64];

  const int tid = threadIdx.x, lane = tid & 63, w = tid >> 6;
  const int mw = w & 3, nw = w >> 2;
  const int bid = blockIdx.x;
  const int nh = (bid >> 3) & 1;                // pair ids differ by 8 -> same XCD
  const int bg = ((bid >> 4) << 3) | (bid & 7);
  const int bb0 = bg * 4;

  f32x4 acc[MFW][8];
#pragma unroll
  for (int m = 0; m < MFW; ++m)
#pragma unroll
    for (int n = 0; n < 8; ++n) acc[m][n] = (f32x4){0.f, 0.f, 0.f, 0.f};

  float4 sF[ASL][2];
  u16x8 sH[ASL], sL[ASL];
  u16x8 sB[4];

  auto LOADS = [&](int ks2) {
    const int kk2 = ks2 >> 4;
    const int c0 = (ks2 & 15) * 32 + ((lane >> 4) << 2);
#pragma unroll
    for (int si = 0; si < ASL; ++si) {
      const int f = w + si * 8;
      if (f < MFT) {
        const int bA = f / MFW, mfA = f % MFW;
        int t = mfA * 16 + (lane & 15) - 1 + kk2;
        t = t < 0 ? 0 : (t > ROWS - 1 ? ROWS - 1 : t);
        const size_t o = ((size_t)(bb0 + bA) * ROWS + t) * 512 + c0;
        if constexpr (SRCF32) {
          sF[si][0] = *(const float4*)(xf + o);
          sF[si][1] = *(const float4*)(xf + o + 16);
        } else {
          const u16x4 a = *(const u16x4*)(ghi + o);
          const u16x4 b = *(const u16x4*)(ghi + o + 16);
          const u16x4 c = *(const u16x4*)(glo + o);
          const u16x4 d = *(const u16x4*)(glo + o + 16);
          sH[si] = (u16x8){a[0], a[1], a[2], a[3], b[0], b[1], b[2], b[3]};
          sL[si] = (u16x8){c[0], c[1], c[2], c[3], d[0], d[1], d[2], d[3]};
        }
      }
    }
#pragma unroll
    for (int ci = 0; ci < 4; ++ci) {
      const int cch = w + ci * 8;
      const int p = cch >> 4, nf = cch & 15;
      sB[ci] = *(const u16x8*)(wl + ((size_t)(((nh * 2 + p) * 48 + ks2) * 16 + nf)) * 512 + lane * 8);
    }
  };

  auto WRITES = [&](int nb) {
#pragma unroll
    for (int si = 0; si < ASL; ++si) {
      const int f = w + si * 8;
      if (f < MFT) {
        u16x8 hv, lv;
        if constexpr (SRCF32) {
          float vv[8] = {sF[si][0].x, sF[si][0].y, sF[si][0].z, sF[si][0].w,
                         sF[si][1].x, sF[si][1].y, sF[si][1].z, sF[si][1].w};
#pragma unroll
          for (int e = 0; e < 8; ++e) {
            const u16 h = bf16rne(vv[e]);
            hv[e] = h;
            lv[e] = bf16rne(vv[e] - bf16tof(h));
          }
        } else {
          hv = sH[si];
          lv = sL[si];
        }
        Ald[nb][0][f][lane] = hv;
        Ald[nb][1][f][lane] = lv;
      }
    }
#pragma unroll
    for (int ci = 0; ci < 4; ++ci) {
      const int cch = w + ci * 8;
      Bld[nb][cch >> 4][cch & 15][lane] = sB[ci];
    }
  };

  LOADS(0);
  WRITES(0);
  __syncthreads();

  for (int ks = 0; ks < 48; ++ks) {
    const int buf = ks & 1;
    if (ks < 47) LOADS(ks + 1);
    u16x8 ah[MFW], al[MFW];
#pragma unroll
    for (int m = 0; m < MFW; ++m) {
      ah[m] = Ald[buf][0][mw * MFW + m][lane];
      al[m] = Ald[buf][1][mw * MFW + m][lane];
    }
    __builtin_amdgcn_s_setprio(1);
#pragma unroll
    for (int n = 0; n < 8; ++n) {
      const u16x8 bh = Bld[buf][0][nw * 8 + n][lane];
      const u16x8 bl = Bld[buf][1][nw * 8 + n][lane];
#pragma unroll
      for (int m = 0; m < MFW; ++m) {
        acc[m][n] = mfma16(ah[m], bh, acc[m][n]);
        acc[m][n] = mfma16(ah[m], bl, acc[m][n]);
        acc[m][n] = mfma16(al[m], bh, acc[m][n]);
      }
    }
    __builtin_amdgcn_s_setprio(0);
    if (ks < 47) WRITES(buf ^ 1);
    __syncthreads();
  }

  const int b = bb0 + mw;
#pragma unroll
  for (int m = 0; m < MFW; ++m) {
#pragma unroll
    for (int n = 0; n < 8; ++n) {
      const int col = nh * 256 + nw * 128 + n * 16 + (lane & 15);
      const float bs = bias[col];
#pragma unroll
      for (int r = 0; r < 4; ++r) {
        const int t = m * 16 + ((lane >> 4) << 2) + r;
        if (t < ROWS) {
          float v = acc[m][n][r] + bs;
          if (RELU) v = fmaxf(v, 0.f);
          const size_t o = ((size_t)b * ROWS + t) * 512 + col;
          if constexpr (F32OUT) {
            of32[o] = v;
          } else {
            const u16 h = bf16rne(v);
            ohi[o] = h;
            olo[o] = bf16rne(v - bf16tof(h));
          }
        }
      }
    }
  }
}

// ---------------- tok_mix (round-2 form) ------------------------------------
__global__ __launch_bounds__(512, 2)
void tok_mix(const u16* __restrict__ h1hi, const u16* __restrict__ h1lo,
             const u16* __restrict__ twf, const float* __restrict__ tok_b,
             u16* __restrict__ g1hi, u16* __restrict__ g1lo) {
  __shared__ float h1f[64][258];
  __shared__ u16x8 twl[2][2][4][64];
  __shared__ float tbl[64];
  const int tid = threadIdx.x, lane = tid & 63, w = tid >> 6;
  const int mw = w & 3, nw = w >> 2;
  const int b = blockIdx.y, ch = blockIdx.x;

  for (int i = tid; i < 1024; i += 512) ((u16x8*)twl)[i] = ((const u16x8*)twf)[i];
  if (tid < 64) tbl[tid] = tok_b[tid];
  for (int i = tid; i < 2048; i += 512) {
    const int t = i >> 5, c8 = (i & 31) * 8;
    const size_t o = ((size_t)b * 64 + t) * 512 + ch * 256 + c8;
    const u16x8 hv = *(const u16x8*)(h1hi + o);
    const u16x8 lv = *(const u16x8*)(h1lo + o);
#pragma unroll
    for (int e = 0; e < 8; ++e) h1f[t][c8 + e] = bf16tof(hv[e]) + bf16tof(lv[e]);
  }
  __syncthreads();

  f32x4 acc2[8];
#pragma unroll
  for (int n = 0; n < 8; ++n) acc2[n] = (f32x4){0.f, 0.f, 0.f, 0.f};
#pragma unroll
  for (int ksI = 0; ksI < 2; ++ksI) {
    const u16x8 ah = twl[0][ksI][mw][lane];
    const u16x8 al = twl[1][ksI][mw][lane];
    const int t0 = ksI * 32 + ((lane >> 4) << 2);
#pragma unroll
    for (int n = 0; n < 8; ++n) {
      const int c = nw * 128 + n * 16 + (lane & 15);
      u16x8 bh, bl;
#pragma unroll
      for (int e = 0; e < 8; ++e) {
        const float v = h1f[t0 + (e & 3) + ((e >> 2) << 4)][c];
        const u16 h = bf16rne(v);
        bh[e] = h;
        bl[e] = bf16rne(v - bf16tof(h));
      }
      acc2[n] = mfma16(ah, bh, acc2[n]);
      acc2[n] = mfma16(ah, bl, acc2[n]);
      acc2[n] = mfma16(al, bh, acc2[n]);
    }
  }
  __syncthreads();
#pragma unroll
  for (int n = 0; n < 8; ++n) {
    const int c = nw * 128 + n * 16 + (lane & 15);
#pragma unroll
    for (int r = 0; r < 4; ++r) {
      const int s = mw * 16 + ((lane >> 4) << 2) + r;
      h1f[s][c] = fmaxf(acc2[n][r] + tbl[s], 0.f);
    }
  }
  __syncthreads();
  const float scale = (float)(64.0 / 50.0);
  for (int i = tid; i < 50 * 256; i += 512) {
    const int s = i >> 8, c = i & 255;
    float coords = fminf(fmaxf(((float)s + 0.5f) * scale - 0.5f, 0.f), 63.f);
    const int lo = (int)floorf(coords);
    const int hi = lo + 1 < 64 ? lo + 1 : 63;
    const float wv = coords - (float)lo;
    const float v = h1f[lo][c] * (1.f - wv) + h1f[hi][c] * wv;
    const u16 h = bf16rne(v);
    const size_t o = ((size_t)b * 50 + s) * 512 + ch * 256 + c;
    g1hi[o] = h;
    g1lo[o] = bf16rne(v - bf16tof(h));
  }
}

// ---------------- ginterp (round-2 form) ------------------------------------
template <int SOUT, int SIN>
__global__ __launch_bounds__(256)
void ginterp(const u16* __restrict__ ahi, const u16* __restrict__ alo,
             u16* __restrict__ ghi, u16* __restrict__ glo) {
  const int idx = blockIdx.x * 256 + threadIdx.x;
  if (idx >= 1024 * SOUT * 64) return;
  const int ch = (idx & 63) * 8;
  const int s = (idx >> 6) % SOUT;
  const int b = (idx >> 6) / SOUT;
  const float scale = (float)((double)SIN / (double)SOUT);
  float coords = fminf(fmaxf(((float)s + 0.5f) * scale - 0.5f, 0.f), (float)(SIN - 1));
  const int lo = (int)floorf(coords);
  const int hi = lo + 1 < SIN ? lo + 1 : SIN - 1;
  const float wv = coords - (float)lo;
  const size_t olo_ = ((size_t)b * SIN + lo) * 512 + ch;
  const size_t ohi_ = ((size_t)b * SIN + hi) * 512 + ch;
  const u16x8 vh0 = *(const u16x8*)(ahi + olo_), vl0 = *(const u16x8*)(alo + olo_);
  const u16x8 vh1 = *(const u16x8*)(ahi + ohi_), vl1 = *(const u16x8*)(alo + ohi_);
  u16x8 oh, ol;
#pragma unroll
  for (int e = 0; e < 8; ++e) {
    const float v0 = bf16tof(vh0[e]) + bf16tof(vl0[e]);
    const float v1 = bf16tof(vh1[e]) + bf16tof(vl1[e]);
    const float v = v0 * (1.f - wv) + v1 * wv;
    const u16 h = bf16rne(v);
    oh[e] = h;
    ol[e] = bf16rne(v - bf16tof(h));
  }
  const size_t oo = ((size_t)b * SOUT + s) * 512 + ch;
  *(u16x8*)(ghi + oo) = oh;
  *(u16x8*)(glo + oo) = ol;
}

// ---------------- k_beta (round-2 form) -------------------------------------
__global__ __launch_bounds__(256)
void k_beta(const float* __restrict__ h, const float* __restrict__ ln_g,
            const float* __restrict__ ln_b, const float* __restrict__ beta_w,
            const float* __restrict__ beta_b, float* __restrict__ out) {
  __shared__ float nbuf[512];
  __shared__ float red[32];
  __shared__ float part[160];
  const int tid = threadIdx.x;
  const int b = blockIdx.x;
  const float* hb = h + (size_t)b * (22 * 512);
  float m0 = 0.f, m1 = 0.f;
  for (int t = 0; t < 22; ++t) {
    m0 += hb[t * 512 + tid];
    m1 += hb[t * 512 + tid + 256];
  }
  m0 *= (1.f / 22.f);
  m1 *= (1.f / 22.f);
  float s = m0 + m1, sq = m0 * m0 + m1 * m1;
  for (int off = 32; off > 0; off >>= 1) {
    s += __shfl_down(s, off);
    sq += __shfl_down(sq, off);
  }
  const int lane = tid & 63, wid = tid >> 6;
  if (lane == 0) { red[wid] = s; red[8 + wid] = sq; }
  __syncthreads();
  if (tid == 0) {
    float S = red[0] + red[1] + red[2] + red[3];
    float Q = red[8] + red[9] + red[10] + red[11];
    float mu = S * (1.f / 512.f);
    float var = Q * (1.f / 512.f) - mu * mu;
    red[16] = mu;
    red[17] = 1.f / sqrtf(var + 1e-5f);
  }
  __syncthreads();
  const float mu = red[16], rs = red[17];
  nbuf[tid] = (m0 - mu) * rs * ln_g[tid] + ln_b[tid];
  nbuf[tid + 256] = (m1 - mu) * rs * ln_g[tid + 256] + ln_b[tid + 256];
  __syncthreads();
  if (tid < 160) {
    const int o = tid >> 4, l = tid & 15;
    float p = 0.f;
    for (int w = l; w < 512; w += 16) p += nbuf[w] * beta_w[w * 10 + o];
    part[tid] = p;
  }
  __syncthreads();
  if (tid < 10) {
    float p = beta_b[tid];
#pragma unroll
    for (int l = 0; l < 16; ++l) p += part[tid * 16 + l];
    out[(size_t)b * 10 + tid] = p;
  }
}

// ---------------- k_pose1 (round-2 form + XCD pairing) ----------------------
__global__ __launch_bounds__(512, 2)
void k_pose1(const float* __restrict__ hf, const u16* __restrict__ PWF,
             const float* __restrict__ pb1,
             u16* __restrict__ hidhi, u16* __restrict__ hidlo) {
  __shared__ u16x8 Ald[2][2][8][64];
  __shared__ u16x8 Bld[2][2][16][64];
  const int tid = threadIdx.x, lane = tid & 63, w = tid >> 6;
  const int mw = w & 1, nw = w >> 1;
  const int mb = blockIdx.x & 7, nh = blockIdx.x >> 3;  // pair ids differ by 8
  const int j = blockIdx.y;
  const int bb0 = mb * 128;
  const int par = KPAR_C[j];
  const size_t pwbase = (size_t)(j * 2 + nh) * 524288;

  f32x4 acc[4][4];
#pragma unroll
  for (int m = 0; m < 4; ++m)
#pragma unroll
    for (int n = 0; n < 4; ++n) acc[m][n] = (f32x4){0.f, 0.f, 0.f, 0.f};

  float4 sF0, sF1;
  u16x8 sB[4];

  auto LOADS = [&](int ks) {
    const int row = (ks < 16) ? (j + 1) : par;
    const int b = bb0 + w * 16 + (lane & 15);
    const int c0 = (ks & 15) * 32 + ((lane >> 4) << 2);
    const float* src = hf + ((size_t)b * 22 + row) * 512 + c0;
    sF0 = *(const float4*)src;
    sF1 = *(const float4*)(src + 16);
#pragma unroll
    for (int t = 0; t < 4; ++t) {
      const int cc = t * 8 + w;
      const int p = cc >> 4, nf = cc & 15;
      sB[t] = *(const u16x8*)(PWF + pwbase + ((size_t)(p * 32 + ks) * 16 + nf) * 512 + lane * 8);
    }
  };
  auto WRITES = [&](int nb) {
    float vv[8] = {sF0.x, sF0.y, sF0.z, sF0.w, sF1.x, sF1.y, sF1.z, sF1.w};
    u16x8 hv, lv;
#pragma unroll
    for (int e = 0; e < 8; ++e) {
      const u16 h = bf16rne(vv[e]);
      hv[e] = h;
      lv[e] = bf16rne(vv[e] - bf16tof(h));
    }
    Ald[nb][0][w][lane] = hv;
    Ald[nb][1][w][lane] = lv;
#pragma unroll
    for (int t = 0; t < 4; ++t) {
      const int cc = t * 8 + w;
      Bld[nb][cc >> 4][cc & 15][lane] = sB[t];
    }
  };

  LOADS(0);
  WRITES(0);
  __syncthreads();

  for (int ks = 0; ks < 32; ++ks) {
    const int buf = ks & 1;
    if (ks < 31) LOADS(ks + 1);
    u16x8 ah[4], al[4], bh[4], bl[4];
#pragma unroll
    for (int m = 0; m < 4; ++m) {
      ah[m] = Ald[buf][0][mw * 4 + m][lane];
      al[m] = Ald[buf][1][mw * 4 + m][lane];
    }
#pragma unroll
    for (int n = 0; n < 4; ++n) {
      bh[n] = Bld[buf][0][nw * 4 + n][lane];
      bl[n] = Bld[buf][1][nw * 4 + n][lane];
    }
    __builtin_amdgcn_s_setprio(1);
#pragma unroll
    for (int n = 0; n < 4; ++n)
#pragma unroll
      for (int m = 0; m < 4; ++m) {
        acc[m][n] = mfma16(ah[m], bh[n], acc[m][n]);
        acc[m][n] = mfma16(ah[m], bl[n], acc[m][n]);
        acc[m][n] = mfma16(al[m], bh[n], acc[m][n]);
      }
    __builtin_amdgcn_s_setprio(0);
    if (ks < 31) WRITES(buf ^ 1);
    __syncthreads();
  }

#pragma unroll
  for (int m = 0; m < 4; ++m) {
#pragma unroll
    for (int n = 0; n < 4; ++n) {
      const int col = nh * 256 + nw * 64 + n * 16 + (lane & 15);
      const float bs = pb1[(size_t)j * 512 + col];
#pragma unroll
      for (int r = 0; r < 4; ++r) {
        const int b = bb0 + mw * 64 + m * 16 + ((lane >> 4) << 2) + r;
        float v = fmaxf(acc[m][n][r] + bs, 0.f);
        const size_t o = ((size_t)j * 1024 + b) * 512 + col;
        const u16 h = bf16rne(v);
        hidhi[o] = h;
        hidlo[o] = bf16rne(v - bf16tof(h));
      }
    }
  }
}

// ---------------- k_pose2 (round-2 form) ------------------------------------
__global__ __launch_bounds__(256)
void k_pose2(const u16* __restrict__ hidhi, const u16* __restrict__ hidlo,
             const float* __restrict__ pw2, const float* __restrict__ pb2,
             float* __restrict__ out) {
  __shared__ float w2l[3072];
  __shared__ float part[128 * 12];
  const int tid = threadIdx.x;
  const int mb = blockIdx.x, j = blockIdx.y;
  const int bb0 = mb * 128;
  for (int i = tid; i < 3072; i += 256) w2l[i] = pw2[(size_t)j * 3072 + i];
  __syncthreads();

  const int r = tid >> 1, half = tid & 1;
  const int row = bb0 + r;
  const u16* ph = hidhi + ((size_t)j * 1024 + row) * 512 + half * 256;
  const u16* pl = hidlo + ((size_t)j * 1024 + row) * 512 + half * 256;
  float s[6] = {0.f, 0.f, 0.f, 0.f, 0.f, 0.f};
  for (int c = 0; c < 32; ++c) {
    const u16x8 hv = ((const u16x8*)ph)[c];
    const u16x8 lv = ((const u16x8*)pl)[c];
#pragma unroll
    for (int e = 0; e < 8; ++e) {
      const float v = bf16tof(hv[e]) + bf16tof(lv[e]);
      const int hidx = half * 256 + c * 8 + e;
#pragma unroll
      for (int d = 0; d < 6; ++d) s[d] = fmaf(v, w2l[hidx * 6 + d], s[d]);
    }
  }
#pragma unroll
  for (int d = 0; d < 6; ++d) part[r * 12 + half * 6 + d] = s[d];
  __syncthreads();

  if (tid < 128) {
    const int row2 = bb0 + tid;
    float p6[6];
#pragma unroll
    for (int d = 0; d < 6; ++d)
      p6[d] = part[tid * 12 + d] + part[tid * 12 + 6 + d] + pb2[j * 6 + d];
    float* po = out + ((size_t)row2 * 21 + j) * 6;
#pragma unroll
    for (int d = 0; d < 6; ++d) po[d] = p6[d];
    const float a1x = p6[0], a1y = p6[1], a1z = p6[2];
    const float a2x = p6[3], a2y = p6[4], a2z = p6[5];
    const float inv1 = 1.f / sqrtf(a1x * a1x + a1y * a1y + a1z * a1z);
    const float b1x = a1x * inv1, b1y = a1y * inv1, b1z = a1z * inv1;
    const float dot = b1x * a2x + b1y * a2y + b1z * a2z;
    const float px = a2x - dot * b1x, py = a2y - dot * b1y, pz = a2z - dot * b1z;
    const float inv2 = 1.f / sqrtf(px * px + py * py + pz * pz);
    const float b2x = px * inv2, b2y = py * inv2, b2z = pz * inv2;
    const float b3x = b1y * b2z - b1z * b2y;
    const float b3y = b1z * b2x - b1x * b2z;
    const float b3z = b1x * b2y - b1y * b2x;
    float* ro = out + 129024 + ((size_t)row2 * 21 + j) * 9;
    ro[0] = b1x; ro[1] = b1y; ro[2] = b1z;
    ro[3] = b2x; ro[4] = b2y; ro[5] = b2z;
    ro[6] = b3x; ro[7] = b3y; ro[8] = b3z;
  }
}

// ---------------- launch ----------------------------------------------------
extern "C" void kernel_launch(void* const* d_in, const int* in_sizes, int n_in,
                              void* d_out, int out_size, void* d_ws, size_t ws_size,
                              hipStream_t stream) {
  (void)in_sizes; (void)n_in; (void)out_size; (void)ws_size;
  const float* x       = (const float*)d_in[0];
  const float* conv1_w = (const float*)d_in[1];
  const float* conv1_b = (const float*)d_in[2];
  const float* tok_w   = (const float*)d_in[3];
  const float* tok_b   = (const float*)d_in[4];
  const float* up_w    = (const float*)d_in[5];
  const float* up_b    = (const float*)d_in[6];
  const float* ln_g    = (const float*)d_in[7];
  const float* ln_b    = (const float*)d_in[8];
  const float* beta_w  = (const float*)d_in[9];
  const float* beta_b  = (const float*)d_in[10];
  const float* pw1     = (const float*)d_in[11];
  const float* pb1     = (const float*)d_in[12];
  const float* pw2     = (const float*)d_in[13];
  const float* pb2     = (const float*)d_in[14];
  float* outp = (float*)d_out;

  char* base = (char*)d_ws;
  u16* WF  = (u16*)base;                            // 12,582,912 B
  u16* TWF = WF + 6291456;                          // 16,384 B
  u16* PA16 = (u16*)(base + 12599296);              // 134,217,728 B pool A
  u16* PB16 = (u16*)(base + 12599296 + 134217728);  // 104,857,600 B pool B
  u16* h1hi = PA16;            u16* h1lo = PA16 + 33554432;
  u16* a2hi = PA16;            u16* a2lo = PA16 + 26214400;
  u16* a3hi = PA16;            u16* a3lo = PA16 + 18874368;
  float* hf = (float*)PA16;
  u16* g1hi = PB16;            u16* g1lo = PB16 + 26214400;
  u16* g2hi = PB16;            u16* g2lo = PB16 + 18874368;
  u16* g3hi = PB16;            u16* g3lo = PB16 + 11534336;
  u16* PWF   = PB16;
  u16* hidhi = PB16 + 22020096;
  u16* hidlo = PB16 + 33030144;

  const size_t WL = 1572864;

  kwprep<<<3076, 256, 0, stream>>>(conv1_w, up_w, tok_w, WF, TWF);
  conv_gemm<64, 64, true, false, true><<<512, 512, 0, stream>>>(
      x, nullptr, nullptr, WF, conv1_b, h1hi, h1lo, nullptr);
  tok_mix<<<dim3(2, 1024), 512, 0, stream>>>(h1hi, h1lo, TWF, tok_b, g1hi, g1lo);
  conv_gemm<64, 50, false, false, true><<<512, 512, 0, stream>>>(
      nullptr, g1hi, g1lo, WF + WL, up_b, a2hi, a2lo, nullptr);
  ginterp<36, 50><<<9216, 256, 0, stream>>>(a2hi, a2lo, g2hi, g2lo);
  conv_gemm<48, 36, false, false, true><<<512, 512, 0, stream>>>(
      nullptr, g2hi, g2lo, WF + 2 * WL, up_b + 512, a3hi, a3lo, nullptr);
  ginterp<22, 36><<<5632, 256, 0, stream>>>(a3hi, a3lo, g3hi, g3lo);
  conv_gemm<32, 22, false, true, false><<<512, 512, 0, stream>>>(
      nullptr, g3hi, g3lo, WF + 3 * WL, up_b + 1024, nullptr, nullptr, hf);
  kpw1prep<<<10752, 256, 0, stream>>>(pw1, PWF);
  k_pose1<<<dim3(16, 21), 512, 0, stream>>>(hf, PWF, pb1, hidhi, hidlo);
  k_beta<<<1024, 256, 0, stream>>>(hf, ln_g, ln_b, beta_w, beta_b, outp + 322560);
  k_pose2<<<dim3(8, 21), 256, 0, stream>>>(hidhi, hidlo, pw2, pb2, outp);
}